// Round 14
// baseline (174.721 us; speedup 1.0000x reference)
//
#include <hip/hip_runtime.h>
#include <cstdint>
#include <cstddef>

using f16   = _Float16;
using half4 = __attribute__((ext_vector_type(4))) _Float16;
using half8 = __attribute__((ext_vector_type(8))) _Float16;
using f32x4 = __attribute__((ext_vector_type(4))) float;
using ull   = unsigned long long;

#define DINL __device__ __forceinline__

// global -> LDS async, 16B per lane. LDS dest wave-uniform base + lane*16.
DINL void gload_lds16(const void* gptr, void* lptr) {
  __builtin_amdgcn_global_load_lds(
      reinterpret_cast<const __attribute__((address_space(1))) uint32_t*>(
          reinterpret_cast<uintptr_t>(gptr)),
      reinterpret_cast<__attribute__((address_space(3))) uint32_t*>(
          reinterpret_cast<uintptr_t>(lptr)),
      16, 0, 0);
}

DINL unsigned pkh(float a, float b) {
  unsigned short ha = __builtin_bit_cast(unsigned short, (f16)a);
  unsigned short hb = __builtin_bit_cast(unsigned short, (f16)b);
  return (unsigned)ha | ((unsigned)hb << 16);
}

struct U4 { unsigned x, y, z, w; };

// x -> 16B A-row: [B0..B5 uniform cubic B-spline, silu(x), 0] as 8 f16.
// Funnel-shift placement; validated rounds 5-13 (absmax 0.03125).
DINL U4 expand_pack(float x) {
  float xs = (x + 3.0f) * 1.5f;
  float mf = floorf(xs);
  int   m  = (int)mf;
  float u = xs - mf, u2 = u * u, u3 = u2 * u, um = 1.0f - u;
  float p3 = u3 * (1.0f / 6.0f);
  float p2 = (1.0f + 3.0f * (u + u2 - u3)) * (1.0f / 6.0f);
  float p1 = (4.0f - 6.0f * u2 + 3.0f * u3) * (1.0f / 6.0f);
  float p0 = um * um * um * (1.0f / 6.0f);
  ull P = (ull)pkh(p0, p1) | ((ull)pkh(p2, p3) << 32);
  if ((unsigned)m > 8u) P = 0;
  int s    = m * 16 - 48;
  int sneg = min(63, max(0, -s));
  int spos = min(63, max(0, s));
  int shi2 = min(63, max(0, s - 64));
  ull rlo = (s < 0) ? (P >> sneg) : ((s < 64) ? (P << spos) : 0ull);
  ull rhi = (s < 0) ? 0ull
                    : ((s < 64) ? ((P >> (63 - spos)) >> 1) : (P << shi2));
  float sil = x / (1.0f + __expf(-x));
  U4 r;
  r.x = (unsigned)rlo;
  r.y = (unsigned)(rlo >> 32);
  r.z = (unsigned)rhi;
  r.w = pkh(sil, 0.0f);
  return r;
}

// Weight prep, PRE-SWIZZLED (rule 21): dim slot stored at (d&7)^(n&7) so a
// linear global_load_lds yields the swizzled LDS tile. Validated rounds 2-11.
__global__ __launch_bounds__(256)
void prep_w_kernel(const float* __restrict__ coef, const float* __restrict__ ssp,
                   const float* __restrict__ sb, f16* __restrict__ Wt,
                   int Din, int Dout) {
  int idx = blockIdx.x * 256 + threadIdx.x;
  if (idx >= Din * Dout) return;
  int n = idx / Din;
  int d = idx - n * Din;
  float s = ssp[(size_t)d * Dout + n];
  const float* c = coef + ((size_t)d * Dout + n) * 6;
  half8 wv;
#pragma unroll
  for (int b = 0; b < 6; ++b) wv[b] = (f16)(c[b] * s);
  wv[6] = (f16)sb[(size_t)d * Dout + n];
  wv[7] = (f16)0.0f;
  int dp = (d & ~7) | ((d & 7) ^ (n & 7));
  *reinterpret_cast<half8*>(Wt + ((size_t)n * Din + dp) * 8) = wv;
}

// ---------------------------------------------------------------------------
// Fused KAN GEMM v14 = v11 (best: 52us/GEMM) with B SINGLE-buffered:
// LDS 80KB -> 48KB -> 3 blocks/CU (24 waves/CU, +50% TLP). Schedule becomes
// 2-barrier/step (m97-style, plain __syncthreads, race-free by construction):
//   compute(s) -> barrier -> [stageB(s+1) async || expand+ds_write A(s+1)]
//   -> barrier (drains stage).
// The expand between the barriers covers the B-stage L2 latency in-block;
// 3 resident blocks cover the rest. A dbuf, pre-swizzled Wt, f16 h1/partials,
// setprio, x-prefetch all unchanged. Numerics identical (absmax 0.03125).
// ---------------------------------------------------------------------------
template <bool BIAS, typename TIN, typename TOUT>
__global__ __launch_bounds__(512, 6)
void kan_gemm(const TIN* __restrict__ X, int ldx,
              const f16* __restrict__ Wt, int ldw,
              const float* __restrict__ nscale, const float* __restrict__ nbias,
              int N, TOUT* __restrict__ Out, int nsteps) {
  __shared__ alignas(16) f16 A0[64 * 64];      //  8 KB
  __shared__ alignas(16) f16 A1[64 * 64];      //  8 KB
  __shared__ alignas(16) f16 BB[256 * 64];     // 32 KB (single buffer)

  const int tid  = threadIdx.x;
  const int w    = tid >> 6;
  const int lane = tid & 63;
  const int l15  = lane & 15, l7 = lane & 7, hi = lane >> 4;
  const int wm   = w >> 2, wn = w & 3;         // wave grid 2 x 4
  const int m0   = blockIdx.y * 64;
  const int n0   = blockIdx.x * 256;
  const int dim0 = blockIdx.z * (nsteps * 8);  // split-K dim offset
  TOUT* outz = Out + (size_t)blockIdx.z * ((size_t)gridDim.y * 64) * N;

  // A: 1 element/thread/step (64 rows x 8 dims = 512); asrc is DIM-indexed.
  const int ar = tid >> 3, ad = tid & 7;
  const TIN* asrc = X + (size_t)(m0 + ar) * ldx + dim0 + ad;
  const int aoff = ar * 64 + 8 * (ad ^ (ar & 7));

  // B: 4 x 16B chunks/thread (256 rows x 8 slots = 2048 chunks)
  const f16* wb[4];
  int ldsb[4];
#pragma unroll
  for (int q = 0; q < 4; ++q) {
    int c   = tid + q * 512;
    wb[q]   = Wt + (size_t)(n0 + (c >> 3)) * ldw + (size_t)dim0 * 8 + (c & 7) * 8;
    ldsb[q] = c * 8;
  }

  f32x4 acc[2][4] = {};

  auto stageB = [&](int k0) {
#pragma unroll
    for (int q = 0; q < 4; ++q) gload_lds16(wb[q] + k0, BB + ldsb[q]);
  };

  auto compute = [&](const f16* bA) {
    __builtin_amdgcn_s_setprio(1);
#pragma unroll
    for (int kk = 0; kk < 2; ++kk) {
      const int sl = kk * 4 + hi;
      half8 av[2], bv[4];
#pragma unroll
      for (int i = 0; i < 2; ++i)
        av[i] = *reinterpret_cast<const half8*>(
            bA + (wm * 32 + i * 16 + l15) * 64 + 8 * (sl ^ l7));
#pragma unroll
      for (int j = 0; j < 4; ++j)
        bv[j] = *reinterpret_cast<const half8*>(
            BB + (wn * 64 + j * 16 + l15) * 64 + 8 * (sl ^ l7));
#pragma unroll
      for (int i = 0; i < 2; ++i)
#pragma unroll
        for (int j = 0; j < 4; ++j)
          acc[i][j] = __builtin_amdgcn_mfma_f32_16x16x32_f16(av[i], bv[j], acc[i][j], 0, 0, 0);
    }
    __builtin_amdgcn_s_setprio(0);
  };

  auto writeA = [&](f16* buf, U4 e) {
    *reinterpret_cast<U4*>(buf + aoff) = e;
  };

  // ---- prologue: A(0)->A0, B(0)->BB; xn = x(1) in flight ----
  {
    float xa = (float)asrc[0];
    stageB(0);
    writeA(A0, expand_pack(xa));
  }
  float xn = (float)asrc[8];
  __syncthreads();                             // drains B(0) stage + x loads

  // ---- steady state: 2 steps/iter, static A names, single B ----
  const int npairs = (nsteps - 2) >> 1;        // pairs cover s=0..nsteps-3
  int k = 0;                                   // f16 k-elem offset of step s
  int kd = 0;                                  // dim offset of step s
  for (int p = 0; p < npairs; ++p) {
    // s even: compute A0/B(s); then stage B(s+1) || expand x(s+1)->A1
    float xa2 = (float)asrc[kd + 16];          // x(s+2), issued early
    compute(A0);
    __syncthreads();                           // B(s) reads done
    stageB(k + 64);
    writeA(A1, expand_pack(xn));
    __syncthreads();                           // B(s+1), A(s+1) visible
    // s+1 odd: compute A1/B(s+1); stage B(s+2) || expand x(s+2)->A0
    float xb2 = (float)asrc[kd + 24];          // x(s+3), issued early
    compute(A1);
    __syncthreads();
    stageB(k + 128);
    writeA(A0, expand_pack(xa2));
    __syncthreads();
    xn = xb2;
    k += 128;
    kd += 16;
  }

  // ---- tail: s = nsteps-2 (A0), then s = nsteps-1 (A1) ----
  compute(A0);
  __syncthreads();
  stageB(k + 64);                              // == (nsteps-1)*64
  writeA(A1, expand_pack(xn));
  __syncthreads();
  compute(A1);

  // ---- epilogue: Out = ns*acc (+ nb) ----
#pragma unroll
  for (int j = 0; j < 4; ++j) {
    int col   = n0 + wn * 64 + j * 16 + l15;
    float nsv = nscale[col];
    float nbv = BIAS ? nbias[col] : 0.0f;
#pragma unroll
    for (int i = 0; i < 2; ++i) {
      int rb = m0 + wm * 32 + i * 16 + hi * 4;
#pragma unroll
      for (int r = 0; r < 4; ++r)
        outz[(size_t)(rb + r) * N + col] = (TOUT)(nsv * acc[i][j][r] + nbv);
    }
  }
}

// ---------------------------------------------------------------------------
// f16 partial0 + f16 partial1 + node_bias2 + residual -> LN(256) -> exact GELU
// ---------------------------------------------------------------------------
__global__ __launch_bounds__(256)
void ln_gelu_kernel(const f16* __restrict__ P0, const f16* __restrict__ P1,
                    const float* __restrict__ X,  const float* __restrict__ nb2,
                    const float* __restrict__ gamma, const float* __restrict__ beta,
                    float* __restrict__ out, int rows) {
  int row  = blockIdx.x * 4 + (threadIdx.x >> 6);
  int lane = threadIdx.x & 63;
  if (row >= rows) return;
  const half4  a4 = *reinterpret_cast<const half4*>(P0 + (size_t)row * 256 + lane * 4);
  const half4  b4 = *reinterpret_cast<const half4*>(P1 + (size_t)row * 256 + lane * 4);
  const float4 xr = *reinterpret_cast<const float4*>(X  + (size_t)row * 256 + lane * 4);
  const float4 nb = *reinterpret_cast<const float4*>(nb2 + lane * 4);
  const float4 g  = *reinterpret_cast<const float4*>(gamma + lane * 4);
  const float4 be = *reinterpret_cast<const float4*>(beta + lane * 4);
  float h[4];
#pragma unroll
  for (int j = 0; j < 4; ++j)
    h[j] = (float)a4[j] + (float)b4[j] + (&nb.x)[j] + (&xr.x)[j];
  float s = h[0] + h[1] + h[2] + h[3];
#pragma unroll
  for (int o = 32; o >= 1; o >>= 1) s += __shfl_xor(s, o);
  float mu = s * (1.0f / 256.0f);
  float vs = 0.f;
#pragma unroll
  for (int j = 0; j < 4; ++j) { float d = h[j] - mu; vs += d * d; }
#pragma unroll
  for (int o = 32; o >= 1; o >>= 1) vs += __shfl_xor(vs, o);
  float inv = rsqrtf(vs * (1.0f / 256.0f) + 1e-5f);
  float o4[4];
#pragma unroll
  for (int j = 0; j < 4; ++j) {
    float v = (h[j] - mu) * inv * (&g.x)[j] + (&be.x)[j];
    o4[j] = 0.5f * v * (1.0f + erff(v * 0.70710678118654752f));
  }
  *reinterpret_cast<float4*>(out + (size_t)row * 256 + lane * 4) =
      make_float4(o4[0], o4[1], o4[2], o4[3]);
}

// ---------------------------------------------------------------------------
extern "C" void kernel_launch(void* const* d_in, const int* in_sizes, int n_in,
                              void* d_out, int out_size, void* d_ws, size_t ws_size,
                              hipStream_t stream) {
  (void)in_sizes; (void)n_in; (void)out_size; (void)ws_size;
  const float* x     = (const float*)d_in[0];
  const float* coef1 = (const float*)d_in[2];
  const float* sb1   = (const float*)d_in[3];
  const float* ssp1  = (const float*)d_in[4];
  const float* ns1   = (const float*)d_in[5];
  const float* nb1   = (const float*)d_in[6];
  const float* coef2 = (const float*)d_in[8];
  const float* sb2   = (const float*)d_in[9];
  const float* ssp2  = (const float*)d_in[10];
  const float* ns2   = (const float*)d_in[11];
  const float* nb2   = (const float*)d_in[12];
  const float* lgam  = (const float*)d_in[13];
  const float* lbet  = (const float*)d_in[14];
  float* out = (float*)d_out;

  const int Ntok = 16 * 1024;
  const int D0 = 256, D1 = 512, D2 = 256;

  // ws: h1 [Ntok,512] f16 | part [2][Ntok,256] f16 | Wt1 2MB | Wt2 2MB
  char* ws    = (char*)d_ws;
  f16*  h1    = (f16*)ws;
  size_t off  = (size_t)Ntok * D1 * sizeof(f16);
  f16*  part  = (f16*)(ws + off);
  off += (size_t)2 * Ntok * D2 * sizeof(f16);
  f16* Wt1 = (f16*)(ws + off);
  off += (size_t)D1 * D0 * 8 * sizeof(f16);
  f16* Wt2 = (f16*)(ws + off);

  prep_w_kernel<<<(D0 * D1 + 255) / 256, 256, 0, stream>>>(coef1, ssp1, sb1, Wt1, D0, D1);
  prep_w_kernel<<<(D1 * D2 + 255) / 256, 256, 0, stream>>>(coef2, ssp2, sb2, Wt2, D1, D2);

  // layer 1: [16384 x 2048] x [512 x 2048]^T -> h1 (f16). 512 blocks, 3/CU.
  kan_gemm<true, float, f16><<<dim3(D1 / 256, Ntok / 64, 1), 512, 0, stream>>>(
      x, D0, Wt1, D0 * 8, ns1, nb1, D1, h1, D0 / 8);

  // layer 2: full-width N=256, split-K=2 -> 512 blocks; f16 partials ns2*acc.
  kan_gemm<false, f16, f16><<<dim3(D2 / 256, Ntok / 64, 2), 512, 0, stream>>>(
      h1, D1, Wt2, D1 * 8, ns2, nullptr, D2, part, D1 / 16);

  // reduce partials + bias + residual + LN + GELU
  ln_gelu_kernel<<<Ntok / 4, 256, 0, stream>>>(
      part, part + (size_t)Ntok * D2, x, nb2, lgam, lbet, out, Ntok);
}

// Round 15
// 119.712 us; speedup vs baseline: 1.4595x; 1.4595x over previous
//
#include <hip/hip_runtime.h>
#include <cstdint>
#include <cstddef>

using f16   = _Float16;
using half4 = __attribute__((ext_vector_type(4))) _Float16;
using half8 = __attribute__((ext_vector_type(8))) _Float16;
using f32x4 = __attribute__((ext_vector_type(4))) float;
using ull   = unsigned long long;

#define DINL __device__ __forceinline__

// global -> LDS async, 16B per lane. LDS dest wave-uniform base + lane*16.
DINL void gload_lds16(const void* gptr, void* lptr) {
  __builtin_amdgcn_global_load_lds(
      reinterpret_cast<const __attribute__((address_space(1))) uint32_t*>(
          reinterpret_cast<uintptr_t>(gptr)),
      reinterpret_cast<__attribute__((address_space(3))) uint32_t*>(
          reinterpret_cast<uintptr_t>(lptr)),
      16, 0, 0);
}

DINL unsigned pkh(float a, float b) {
  unsigned short ha = __builtin_bit_cast(unsigned short, (f16)a);
  unsigned short hb = __builtin_bit_cast(unsigned short, (f16)b);
  return (unsigned)ha | ((unsigned)hb << 16);
}

struct U4 { unsigned x, y, z, w; };

// x -> 16B A-row: [B0..B5 uniform cubic B-spline, silu(x), 0] as 8 f16.
// Funnel-shift placement; validated rounds 5-14 (absmax 0.03125).
DINL U4 expand_pack(float x) {
  float xs = (x + 3.0f) * 1.5f;
  float mf = floorf(xs);
  int   m  = (int)mf;
  float u = xs - mf, u2 = u * u, u3 = u2 * u, um = 1.0f - u;
  float p3 = u3 * (1.0f / 6.0f);
  float p2 = (1.0f + 3.0f * (u + u2 - u3)) * (1.0f / 6.0f);
  float p1 = (4.0f - 6.0f * u2 + 3.0f * u3) * (1.0f / 6.0f);
  float p0 = um * um * um * (1.0f / 6.0f);
  ull P = (ull)pkh(p0, p1) | ((ull)pkh(p2, p3) << 32);
  if ((unsigned)m > 8u) P = 0;
  int s    = m * 16 - 48;
  int sneg = min(63, max(0, -s));
  int spos = min(63, max(0, s));
  int shi2 = min(63, max(0, s - 64));
  ull rlo = (s < 0) ? (P >> sneg) : ((s < 64) ? (P << spos) : 0ull);
  ull rhi = (s < 0) ? 0ull
                    : ((s < 64) ? ((P >> (63 - spos)) >> 1) : (P << shi2));
  float sil = x / (1.0f + __expf(-x));
  U4 r;
  r.x = (unsigned)rlo;
  r.y = (unsigned)(rlo >> 32);
  r.z = (unsigned)rhi;
  r.w = pkh(sil, 0.0f);
  return r;
}

// Weight prep, PRE-SWIZZLED (rule 21): dim slot stored at (d&7)^(n&7) so a
// linear global_load_lds yields the swizzled LDS tile. Validated rounds 2-14.
__global__ __launch_bounds__(256)
void prep_w_kernel(const float* __restrict__ coef, const float* __restrict__ ssp,
                   const float* __restrict__ sb, f16* __restrict__ Wt,
                   int Din, int Dout) {
  int idx = blockIdx.x * 256 + threadIdx.x;
  if (idx >= Din * Dout) return;
  int n = idx / Din;
  int d = idx - n * Din;
  float s = ssp[(size_t)d * Dout + n];
  const float* c = coef + ((size_t)d * Dout + n) * 6;
  half8 wv;
#pragma unroll
  for (int b = 0; b < 6; ++b) wv[b] = (f16)(c[b] * s);
  wv[6] = (f16)sb[(size_t)d * Dout + n];
  wv[7] = (f16)0.0f;
  int dp = (d & ~7) | ((d & 7) ^ (n & 7));
  *reinterpret_cast<half8*>(Wt + ((size_t)n * Din + dp) * 8) = wv;
}

// ---------------------------------------------------------------------------
// Fused KAN GEMM v15 = v11 with a 64x64 WAVE TILE (4 waves/block instead of
// 8), cutting LDS-pipe traffic per block-step 136KB -> 88KB (the measured
// bottleneck: ~32us/GEMM of LDS time at v11's 32x64 tile). Same BM=64 x
// BN=256 block tile, same 80KB dbuf LDS, same 1-barrier/step schedule, same
// pre-swizzled B staging and expand numerics (absmax 0.03125).
// launch_bounds(256,2): VGPR cap 256 — no spill (r14 lesson).
// ---------------------------------------------------------------------------
template <bool BIAS, typename TIN, typename TOUT>
__global__ __launch_bounds__(256, 2)
void kan_gemm(const TIN* __restrict__ X, int ldx,
              const f16* __restrict__ Wt, int ldw,
              const float* __restrict__ nscale, const float* __restrict__ nbias,
              int N, TOUT* __restrict__ Out, int nsteps) {
  __shared__ alignas(16) f16 A0[64 * 64];      //  8 KB
  __shared__ alignas(16) f16 A1[64 * 64];      //  8 KB
  __shared__ alignas(16) f16 B0[256 * 64];     // 32 KB
  __shared__ alignas(16) f16 B1[256 * 64];     // 32 KB

  const int tid  = threadIdx.x;
  const int w    = tid >> 6;                   // 4 waves, wave tile 64x64
  const int lane = tid & 63;
  const int l15  = lane & 15, l7 = lane & 7, hi = lane >> 4;
  const int m0   = blockIdx.y * 64;
  const int n0   = blockIdx.x * 256;
  const int dim0 = blockIdx.z * (nsteps * 8);  // split-K dim offset
  TOUT* outz = Out + (size_t)blockIdx.z * ((size_t)gridDim.y * 64) * N;

  // A staging: 2 elems/thread/step (64 rows x 8 dims = 512; 256 threads).
  const int ar = tid >> 3, ad = tid & 7;       // rows 0..31 / +32
  const TIN* asrc0 = X + (size_t)(m0 + ar) * ldx + dim0 + ad;   // dim-indexed
  const TIN* asrc1 = asrc0 + (size_t)32 * ldx; // (ar+32)&7 == ar&7
  const int aoff0 = ar * 64 + 8 * (ad ^ (ar & 7));
  const int aoff1 = aoff0 + 32 * 64;

  // B staging: 8 x 16B chunks/thread (2048 chunks); chunk c = tid + q*256
  // -> row (tid>>3)+q*32, slot tid&7; dest = linear c*16B (rule 21).
  const f16* wsrc = Wt + (size_t)(n0 + (tid >> 3)) * ldw + (size_t)dim0 * 8 + (tid & 7) * 8;
  f16* const bdst = (f16*)nullptr;             // (placeholder, unused)

  f32x4 acc[4][4] = {};

  auto stageB = [&](f16* buf, int k0) {
#pragma unroll
    for (int q = 0; q < 8; ++q)
      gload_lds16(wsrc + (size_t)q * 32 * ldw + k0, buf + tid * 8 + q * 2048);
  };

  auto compute = [&](const f16* bA, const f16* bB) {
    __builtin_amdgcn_s_setprio(1);
#pragma unroll
    for (int kk = 0; kk < 2; ++kk) {
      const int sl = kk * 4 + hi;
      half8 av[4], bv[4];
#pragma unroll
      for (int i = 0; i < 4; ++i)
        av[i] = *reinterpret_cast<const half8*>(
            bA + (i * 16 + l15) * 64 + 8 * (sl ^ l7));
#pragma unroll
      for (int j = 0; j < 4; ++j)
        bv[j] = *reinterpret_cast<const half8*>(
            bB + (w * 64 + j * 16 + l15) * 64 + 8 * (sl ^ l7));
#pragma unroll
      for (int i = 0; i < 4; ++i)
#pragma unroll
        for (int j = 0; j < 4; ++j)
          acc[i][j] = __builtin_amdgcn_mfma_f32_16x16x32_f16(av[i], bv[j], acc[i][j], 0, 0, 0);
    }
    __builtin_amdgcn_s_setprio(0);
  };

  auto writeA = [&](f16* buf, U4 e0, U4 e1) {
    *reinterpret_cast<U4*>(buf + aoff0) = e0;
    *reinterpret_cast<U4*>(buf + aoff1) = e1;
  };

  // ---- prologue: tile 0 in A0/B0; x(1) in flight ----
  {
    float xa0 = (float)asrc0[0], xa1 = (float)asrc1[0];
    stageB(B0, 0);
    writeA(A0, expand_pack(xa0), expand_pack(xa1));
  }
  float xn0 = (float)asrc0[8], xn1 = (float)asrc1[8];
  __syncthreads();

  // ---- steady state: 2 tiles per iteration, static buffer names ----
  const int npairs = (nsteps - 2) >> 1;
  int k  = 64;                                 // B f16 k-elem offset, step s+1
  int kd = 16;                                 // x dim offset, step s+2
  for (int p = 0; p < npairs; ++p) {
    // step s (even): compute A0/B0; stage B(s+1)->B1; expand x(s+1)->A1
    stageB(B1, k);
    float xa0 = (float)asrc0[kd], xa1 = (float)asrc1[kd];   // x(s+2), early
    compute(A0, B0);
    writeA(A1, expand_pack(xn0), expand_pack(xn1));
    __syncthreads();
    // step s+1 (odd): compute A1/B1; stage B(s+2)->B0; expand x(s+2)->A0
    stageB(B0, k + 64);
    xn0 = (float)asrc0[kd + 8]; xn1 = (float)asrc1[kd + 8]; // x(s+3), early
    compute(A1, B1);
    writeA(A0, expand_pack(xa0), expand_pack(xa1));
    __syncthreads();
    k  += 128;
    kd += 16;
  }

  // ---- tail: tiles nsteps-2 (A0/B0) and nsteps-1 (A1/B1) ----
  stageB(B1, k);                               // k == (nsteps-1)*64
  compute(A0, B0);
  writeA(A1, expand_pack(xn0), expand_pack(xn1));
  __syncthreads();
  compute(A1, B1);

  // ---- epilogue: Out = ns*acc (+ nb) ----
#pragma unroll
  for (int j = 0; j < 4; ++j) {
    int col   = n0 + w * 64 + j * 16 + l15;
    float nsv = nscale[col];
    float nbv = BIAS ? nbias[col] : 0.0f;
#pragma unroll
    for (int i = 0; i < 4; ++i) {
      int rb = m0 + i * 16 + hi * 4;
#pragma unroll
      for (int r = 0; r < 4; ++r)
        outz[(size_t)(rb + r) * N + col] = (TOUT)(nsv * acc[i][j][r] + nbv);
    }
  }
}

// ---------------------------------------------------------------------------
// f16 partial0 + f16 partial1 + node_bias2 + residual -> LN(256) -> exact GELU
// ---------------------------------------------------------------------------
__global__ __launch_bounds__(256)
void ln_gelu_kernel(const f16* __restrict__ P0, const f16* __restrict__ P1,
                    const float* __restrict__ X,  const float* __restrict__ nb2,
                    const float* __restrict__ gamma, const float* __restrict__ beta,
                    float* __restrict__ out, int rows) {
  int row  = blockIdx.x * 4 + (threadIdx.x >> 6);
  int lane = threadIdx.x & 63;
  if (row >= rows) return;
  const half4  a4 = *reinterpret_cast<const half4*>(P0 + (size_t)row * 256 + lane * 4);
  const half4  b4 = *reinterpret_cast<const half4*>(P1 + (size_t)row * 256 + lane * 4);
  const float4 xr = *reinterpret_cast<const float4*>(X  + (size_t)row * 256 + lane * 4);
  const float4 nb = *reinterpret_cast<const float4*>(nb2 + lane * 4);
  const float4 g  = *reinterpret_cast<const float4*>(gamma + lane * 4);
  const float4 be = *reinterpret_cast<const float4*>(beta + lane * 4);
  float h[4];
#pragma unroll
  for (int j = 0; j < 4; ++j)
    h[j] = (float)a4[j] + (float)b4[j] + (&nb.x)[j] + (&xr.x)[j];
  float s = h[0] + h[1] + h[2] + h[3];
#pragma unroll
  for (int o = 32; o >= 1; o >>= 1) s += __shfl_xor(s, o);
  float mu = s * (1.0f / 256.0f);
  float vs = 0.f;
#pragma unroll
  for (int j = 0; j < 4; ++j) { float d = h[j] - mu; vs += d * d; }
#pragma unroll
  for (int o = 32; o >= 1; o >>= 1) vs += __shfl_xor(vs, o);
  float inv = rsqrtf(vs * (1.0f / 256.0f) + 1e-5f);
  float o4[4];
#pragma unroll
  for (int j = 0; j < 4; ++j) {
    float v = (h[j] - mu) * inv * (&g.x)[j] + (&be.x)[j];
    o4[j] = 0.5f * v * (1.0f + erff(v * 0.70710678118654752f));
  }
  *reinterpret_cast<float4*>(out + (size_t)row * 256 + lane * 4) =
      make_float4(o4[0], o4[1], o4[2], o4[3]);
}

// ---------------------------------------------------------------------------
extern "C" void kernel_launch(void* const* d_in, const int* in_sizes, int n_in,
                              void* d_out, int out_size, void* d_ws, size_t ws_size,
                              hipStream_t stream) {
  (void)in_sizes; (void)n_in; (void)out_size; (void)ws_size;
  const float* x     = (const float*)d_in[0];
  const float* coef1 = (const float*)d_in[2];
  const float* sb1   = (const float*)d_in[3];
  const float* ssp1  = (const float*)d_in[4];
  const float* ns1   = (const float*)d_in[5];
  const float* nb1   = (const float*)d_in[6];
  const float* coef2 = (const float*)d_in[8];
  const float* sb2   = (const float*)d_in[9];
  const float* ssp2  = (const float*)d_in[10];
  const float* ns2   = (const float*)d_in[11];
  const float* nb2   = (const float*)d_in[12];
  const float* lgam  = (const float*)d_in[13];
  const float* lbet  = (const float*)d_in[14];
  float* out = (float*)d_out;

  const int Ntok = 16 * 1024;
  const int D0 = 256, D1 = 512, D2 = 256;

  // ws: h1 [Ntok,512] f16 | part [2][Ntok,256] f16 | Wt1 2MB | Wt2 2MB
  char* ws    = (char*)d_ws;
  f16*  h1    = (f16*)ws;
  size_t off  = (size_t)Ntok * D1 * sizeof(f16);
  f16*  part  = (f16*)(ws + off);
  off += (size_t)2 * Ntok * D2 * sizeof(f16);
  f16* Wt1 = (f16*)(ws + off);
  off += (size_t)D1 * D0 * 8 * sizeof(f16);
  f16* Wt2 = (f16*)(ws + off);

  prep_w_kernel<<<(D0 * D1 + 255) / 256, 256, 0, stream>>>(coef1, ssp1, sb1, Wt1, D0, D1);
  prep_w_kernel<<<(D1 * D2 + 255) / 256, 256, 0, stream>>>(coef2, ssp2, sb2, Wt2, D1, D2);

  // layer 1: [16384 x 2048] x [512 x 2048]^T -> h1 (f16). 512 blocks, 2/CU.
  kan_gemm<true, float, f16><<<dim3(D1 / 256, Ntok / 64, 1), 256, 0, stream>>>(
      x, D0, Wt1, D0 * 8, ns1, nb1, D1, h1, D0 / 8);

  // layer 2: full-width N=256, split-K=2 -> 512 blocks; f16 partials ns2*acc.
  kan_gemm<false, f16, f16><<<dim3(D2 / 256, Ntok / 64, 2), 256, 0, stream>>>(
      h1, D1, Wt2, D1 * 8, ns2, nullptr, D2, part, D1 / 16);

  // reduce partials + bias + residual + LN + GELU
  ln_gelu_kernel<<<Ntok / 4, 256, 0, stream>>>(
      part, part + (size_t)Ntok * D2, x, nb2, lgam, lbet, out, Ntok);
}